// Round 8
// baseline (191.531 us; speedup 1.0000x reference)
//
#include <hip/hip_runtime.h>

typedef unsigned short u16;
typedef unsigned int u32;
typedef __attribute__((ext_vector_type(4))) float f32x4;
typedef __attribute__((ext_vector_type(8))) __bf16 bf16x8;
typedef __attribute__((ext_vector_type(2))) __bf16 bf16x2;

#define NEGINF (-1e30f)
#define QSCALE 0.18033688011112042f   // 0.125 * log2(e)

__device__ __forceinline__ u16 f32_to_bf16(float f) {
  union { float f; unsigned int u; } v;
  v.f = f;
  unsigned int u = v.u;
  u += 0x7fffu + ((u >> 16) & 1u);   // RNE
  return (u16)(u >> 16);
}

__device__ __forceinline__ u32 pk_bf16(float a, float b) {
  bf16x2 t;
  t.x = (__bf16)a;
  t.y = (__bf16)b;
  return __builtin_bit_cast(u32, t);
}

__device__ __forceinline__ f32x4 mfma_bf16(bf16x8 a, bf16x8 b, f32x4 c) {
  return __builtin_amdgcn_mfma_f32_16x16x32_bf16(a, b, c, 0, 0, 0);
}

// async global->LDS, 16B per lane, dest = uniform base + lane*16
#define GLOAD_LDS16(g, l) __builtin_amdgcn_global_load_lds( \
    (const __attribute__((address_space(1))) unsigned int*)(g), \
    (__attribute__((address_space(3))) unsigned int*)(l), 16, 0, 0)

// ---------------------------------------------------------------- converts
// in: [K][N] fp32 row-major  ->  out: [N][K] bf16 (transposed)
__global__ void k_tcvt(const float* __restrict__ in, u16* __restrict__ out, int K, int N) {
  int idx = blockIdx.x * blockDim.x + threadIdx.x;
  if (idx >= K * N) return;
  int k = idx / N, n = idx - k * N;
  out[(size_t)n * K + k] = f32_to_bf16(in[idx]);
}

// ---------------------------------------------------------------- QKV GEMM
// BM=128, BN=64, BK=64, 4 waves (2x2), 48KB LDS -> 3 blocks/CU (12 waves).
// A staged from fp32 x: reg-load (issued a full phase early) -> packed bf16
// cvt -> swizzled ds_write_b128. B staged via global_load_lds (pre-swizzled
// source). One __syncthreads per iter (its lgkm+vm drain is the handoff).
// Q pre-scaled by 0.125*log2(e) so attention uses raw exp2.
__global__ __launch_bounds__(256, 3) void k_qkv(
    const float* __restrict__ x, const u16* __restrict__ Bt,
    const float* __restrict__ bias,
    u16* __restrict__ Qb, u16* __restrict__ Kb, u16* __restrict__ Vtb) {
  __shared__ __align__(16) u16 lsA[2 * 8192];   // 2 x 16KB
  __shared__ __align__(16) u16 lsB[2 * 4096];   // 2 x 8KB
  const int tid = threadIdx.x, lane = tid & 63, wv = tid >> 6;
  const int l15 = lane & 15, g = lane >> 4;
  const int wm = wv >> 1, wn = wv & 1;
  // XCD chunked swizzle: 4608 = 8 * 576
  const int bid = (int)blockIdx.x;
  const int wgid = (bid & 7) * 576 + (bid >> 3);
  const int mtile = wgid / 18, ntile = wgid % 18;
  const int mBase = mtile * 128, nBase = ntile * 64;

  // A staging: thread handles row = tid>>1, k-half = tid&1 (32 fp32 = 8 float4)
  const int arow = tid >> 1, ahalf = tid & 1;
  const float* aptr = x + (size_t)(mBase + arow) * 384 + ahalf * 32;
  u32 awbyte[4];
#pragma unroll
  for (int q = 0; q < 4; ++q) {
    int kc = ahalf * 4 + q;
    awbyte[q] = (u32)(arow * 128 + ((kc ^ (arow & 7)) << 4));
  }
  // B staging: 2 chunks/thread, pre-swizzled global source
  size_t boff[2]; u32 bldso[2];
#pragma unroll
  for (int jj = 0; jj < 2; ++jj) {
    int c = jj * 256 + tid;
    int row = c >> 3, kc = (c & 7) ^ (row & 7);
    boff[jj] = (size_t)(nBase + row) * 384 + kc * 8;
    bldso[jj] = (u32)c * 8;
  }

  f32x4 acc[4][2] = {};
  float4 fA[8];

  // prologue: stage tile 0
#pragma unroll
  for (int q = 0; q < 8; ++q)
    fA[q] = *(const float4*)(aptr + (q >> 1) * 8 + (q & 1) * 4);
#pragma unroll
  for (int jj = 0; jj < 2; ++jj)
    GLOAD_LDS16(Bt + boff[jj], lsB + bldso[jj]);
  asm volatile("s_waitcnt vmcnt(0)" ::: "memory");
#pragma unroll
  for (int q = 0; q < 4; ++q) {
    uint4 w;
    w.x = pk_bf16(fA[2*q].x, fA[2*q].y);
    w.y = pk_bf16(fA[2*q].z, fA[2*q].w);
    w.z = pk_bf16(fA[2*q+1].x, fA[2*q+1].y);
    w.w = pk_bf16(fA[2*q+1].z, fA[2*q+1].w);
    *(uint4*)((char*)lsA + awbyte[q]) = w;
  }
  __syncthreads();

#pragma unroll
  for (int t = 0; t < 6; ++t) {
    const int cur = t & 1, nxt = cur ^ 1;
    if (t < 5) {   // issue next-tile loads BEFORE compute: latency hides under MFMA
#pragma unroll
      for (int q = 0; q < 8; ++q)
        fA[q] = *(const float4*)(aptr + (t + 1) * 64 + (q >> 1) * 8 + (q & 1) * 4);
#pragma unroll
      for (int jj = 0; jj < 2; ++jj)
        GLOAD_LDS16(Bt + boff[jj] + (t + 1) * 64, lsB + nxt * 4096 + bldso[jj]);
    }
    const char* bA = (const char*)lsA + cur * 16384;
    const char* bB = (const char*)lsB + cur * 8192;
#pragma unroll
    for (int ks = 0; ks < 2; ++ks) {
      bf16x8 af[4], bfr[2];
#pragma unroll
      for (int i = 0; i < 4; ++i) {
        int row = wm * 64 + i * 16 + l15;
        af[i] = *(const bf16x8*)(bA + row * 128 + (((ks * 4 + g) ^ (row & 7)) << 4));
      }
#pragma unroll
      for (int j = 0; j < 2; ++j) {
        int row = wn * 32 + j * 16 + l15;
        bfr[j] = *(const bf16x8*)(bB + row * 128 + (((ks * 4 + g) ^ (row & 7)) << 4));
      }
#pragma unroll
      for (int i = 0; i < 4; ++i)
#pragma unroll
        for (int j = 0; j < 2; ++j)
          acc[i][j] = mfma_bf16(af[i], bfr[j], acc[i][j]);
    }
    if (t < 5) {
      asm volatile("s_waitcnt vmcnt(0)" ::: "memory");
#pragma unroll
      for (int q = 0; q < 4; ++q) {
        uint4 w;
        w.x = pk_bf16(fA[2*q].x, fA[2*q].y);
        w.y = pk_bf16(fA[2*q].z, fA[2*q].w);
        w.z = pk_bf16(fA[2*q+1].x, fA[2*q+1].y);
        w.w = pk_bf16(fA[2*q+1].z, fA[2*q+1].w);
        *(uint4*)((char*)lsA + nxt * 16384 + awbyte[q]) = w;
      }
    }
    __syncthreads();
  }

  const int part = ntile / 6;            // block-uniform: 0=q 1=k 2=v
  const int cbase = (ntile % 6) * 64;
#pragma unroll
  for (int j = 0; j < 2; ++j) {
    int c = cbase + wn * 32 + j * 16 + l15;
    float bv = bias[nBase + wn * 32 + j * 16 + l15];
    int hh = c >> 6, d = c & 63;
#pragma unroll
    for (int i = 0; i < 4; ++i) {
      int m0 = mBase + wm * 64 + i * 16 + g * 4;
      int bb = m0 >> 8, tt = m0 & 255;
      size_t bhh = (size_t)(bb * 6 + hh);
      if (part == 2) {
        uint2 w;
        w.x = pk_bf16(acc[i][j][0] + bv, acc[i][j][1] + bv);
        w.y = pk_bf16(acc[i][j][2] + bv, acc[i][j][3] + bv);
        *(uint2*)(Vtb + (bhh * 64 + d) * 256 + tt) = w;
      } else if (part == 0) {
#pragma unroll
        for (int r = 0; r < 4; ++r)
          Qb[(bhh * 256 + tt + r) * 64 + d] = f32_to_bf16((acc[i][j][r] + bv) * QSCALE);
      } else {
#pragma unroll
        for (int r = 0; r < 4; ++r)
          Kb[(bhh * 256 + tt + r) * 64 + d] = f32_to_bf16(acc[i][j][r] + bv);
      }
    }
  }
}

// ---------------------------------------------------------------- attention
// One wave per (bh, 32-row strip): 6144 waves, heavy strips first.
// Peak live ~130 VGPR < 168 cap at launch_bounds(64,3); no K-prefetch regs.
__global__ __launch_bounds__(64, 3) void k_attn(
    const u16* __restrict__ Qb, const u16* __restrict__ Kb,
    const u16* __restrict__ Vtb, u16* __restrict__ Ob) {
  __shared__ __align__(16) u16 lsP[32 * 64];   // 4KB: P / O-transpose buffer
  const int lane = threadIdx.x;
  const int l15 = lane & 15, g = lane >> 4;
  const int s = 7 - (int)blockIdx.y;           // strip (32 q-rows), heavy first
  const int bh = blockIdx.x;
  const int b = bh / 6, h = bh % 6;
  const u16* Qh = Qb + (size_t)bh * (256 * 64);
  const u16* Kh = Kb + (size_t)bh * (256 * 64);
  const u16* Vh = Vtb + (size_t)bh * (64 * 256);
  const int ktiles = (s >> 1) + 1;             // causal 64-k tiles
  char* pbuf = (char*)lsP;

  bf16x8 qf[2][2];
#pragma unroll
  for (int ks = 0; ks < 2; ++ks)
#pragma unroll
    for (int iq = 0; iq < 2; ++iq)
      qf[ks][iq] = *(const bf16x8*)(Qh + (size_t)(s * 32 + iq * 16 + l15) * 64 + ks * 32 + g * 8);

  f32x4 o[4][2] = {};            // o[jd][iq] = O^T[d=jd*16+g*4+r][q=iq*16+l15]
  float rl[2] = {0.f, 0.f};

#pragma unroll 1
  for (int kt = 0; kt < ktiles; ++kt) {
    // K tile (A-operand): dies after S-MFMA
    bf16x8 kf[2][4];
#pragma unroll
    for (int ks = 0; ks < 2; ++ks)
#pragma unroll
      for (int jk = 0; jk < 4; ++jk)
        kf[ks][jk] = *(const bf16x8*)(Kh + (size_t)(kt * 64 + jk * 16 + l15) * 64 + ks * 32 + g * 8);

    f32x4 st[4][2] = {};
    __builtin_amdgcn_s_setprio(1);
#pragma unroll
    for (int ks = 0; ks < 2; ++ks)
#pragma unroll
      for (int jk = 0; jk < 4; ++jk)
#pragma unroll
        for (int iq = 0; iq < 2; ++iq)
          st[jk][iq] = mfma_bf16(kf[ks][jk], qf[ks][iq], st[jk][iq]);
    __builtin_amdgcn_s_setprio(0);

    // V[kt] loads; latency hides under the exp/pack block
    bf16x8 vf[2][4];
#pragma unroll
    for (int ks = 0; ks < 2; ++ks)
#pragma unroll
      for (int jd = 0; jd < 4; ++jd)
        vf[ks][jd] = *(const bf16x8*)(Vh + (size_t)(jd * 16 + l15) * 256 + kt * 64 + ks * 32 + g * 8);

    if (kt == ktiles - 1) {
#pragma unroll
      for (int jk = 0; jk < 4; ++jk)
#pragma unroll
        for (int iq = 0; iq < 2; ++iq)
#pragma unroll
          for (int r = 0; r < 4; ++r)
            if (kt * 64 + jk * 16 + g * 4 + r > s * 32 + iq * 16 + l15)
              st[jk][iq][r] = NEGINF;
    }

    float rs[2] = {0.f, 0.f};
#pragma unroll
    for (int jk = 0; jk < 4; ++jk)
#pragma unroll
      for (int iq = 0; iq < 2; ++iq) {
        float p0 = __builtin_amdgcn_exp2f(st[jk][iq][0]);
        float p1 = __builtin_amdgcn_exp2f(st[jk][iq][1]);
        float p2 = __builtin_amdgcn_exp2f(st[jk][iq][2]);
        float p3 = __builtin_amdgcn_exp2f(st[jk][iq][3]);
        rs[iq] += (p0 + p1) + (p2 + p3);
        int q = iq * 16 + l15;
        int byte = (q * 128 + (jk * 16 + g * 4) * 2) ^ ((q & 7) << 4);
        uint2 w;
        w.x = pk_bf16(p0, p1);
        w.y = pk_bf16(p2, p3);
        *(uint2*)(pbuf + byte) = w;
      }
#pragma unroll
    for (int iq = 0; iq < 2; ++iq) {
      float v = rs[iq];
      v += __shfl_xor(v, 16);
      v += __shfl_xor(v, 32);
      rl[iq] += v;
    }

#pragma unroll
    for (int ks = 0; ks < 2; ++ks) {
      bf16x8 pf[2];
#pragma unroll
      for (int iq = 0; iq < 2; ++iq) {
        int q = iq * 16 + l15;
        pf[iq] = *(const bf16x8*)(pbuf + ((q * 128 + ks * 64 + g * 16) ^ ((q & 7) << 4)));
      }
      __builtin_amdgcn_s_setprio(1);
#pragma unroll
      for (int jd = 0; jd < 4; ++jd)
#pragma unroll
        for (int iq = 0; iq < 2; ++iq)
          o[jd][iq] = mfma_bf16(vf[ks][jd], pf[iq], o[jd][iq]);
      __builtin_amdgcn_s_setprio(0);
    }
  }

  // Epilogue: normalize, transpose through LDS, coalesced 16B stores.
#pragma unroll
  for (int iq = 0; iq < 2; ++iq) {
    float inv = 1.0f / rl[iq];
    int q = iq * 16 + l15;
#pragma unroll
    for (int jd = 0; jd < 4; ++jd) {
      uint2 w;
      w.x = pk_bf16(o[jd][iq][0] * inv, o[jd][iq][1] * inv);
      w.y = pk_bf16(o[jd][iq][2] * inv, o[jd][iq][3] * inv);
      int byte = (q * 128 + jd * 32 + g * 8) ^ ((q & 7) << 4);
      *(uint2*)(pbuf + byte) = w;
    }
  }
  asm volatile("s_waitcnt lgkmcnt(0)" ::: "memory");
#pragma unroll
  for (int rep = 0; rep < 4; ++rep) {
    int row = rep * 8 + (lane >> 3);
    int c = lane & 7;
    uint4 v = *(const uint4*)(pbuf + row * 128 + ((c ^ (row & 7)) * 16));
    int t = s * 32 + row;
    *(uint4*)(Ob + ((size_t)(b * 256 + t)) * 384 + h * 64 + c * 8) = v;
  }
}

// ---------------------------------------------------------------- proj GEMM
// BM=128, BN=64, BK=64, 4 waves, 48KB LDS -> 3 blocks/CU. R7-proven
// counted-vmcnt dbuf (resized: 6 loads/thread -> vmcnt(6)).
__global__ __launch_bounds__(256, 3) void k_proj(
    const u16* __restrict__ A, const u16* __restrict__ Bt,
    const float* __restrict__ bias, float* __restrict__ out) {
  __shared__ __align__(16) u16 lsA[2 * 8192];
  __shared__ __align__(16) u16 lsB[2 * 4096];
  const int tid = threadIdx.x, lane = tid & 63, wv = tid >> 6;
  const int l15 = lane & 15, g = lane >> 4;
  const int wm = wv >> 1, wn = wv & 1;
  // XCD chunked swizzle: 1536 = 8 * 192
  const int bid = (int)blockIdx.x;
  const int wgid = (bid & 7) * 192 + (bid >> 3);
  const int mtile = wgid / 6, ntile = wgid % 6;
  const int mBase = mtile * 128, nBase = ntile * 64;

  size_t aoff[4]; u32 aldso[4];
#pragma unroll
  for (int jj = 0; jj < 4; ++jj) {
    int c = jj * 256 + tid;
    int row = c >> 3, kc = (c & 7) ^ (row & 7);
    aoff[jj] = (size_t)(mBase + row) * 384 + kc * 8;
    aldso[jj] = (u32)c * 8;
  }
  size_t boff[2]; u32 bldso[2];
#pragma unroll
  for (int jj = 0; jj < 2; ++jj) {
    int c = jj * 256 + tid;
    int row = c >> 3, kc = (c & 7) ^ (row & 7);
    boff[jj] = (size_t)(nBase + row) * 384 + kc * 8;
    bldso[jj] = (u32)c * 8;
  }

#define STAGE_P(kt, buf) do { \
  _Pragma("unroll") \
  for (int jj = 0; jj < 4; ++jj) \
    GLOAD_LDS16(A + aoff[jj] + (kt), lsA + (buf) * 8192 + aldso[jj]); \
  _Pragma("unroll") \
  for (int jj = 0; jj < 2; ++jj) \
    GLOAD_LDS16(Bt + boff[jj] + (kt), lsB + (buf) * 4096 + bldso[jj]); \
  } while (0)

  f32x4 acc[4][2] = {};
  STAGE_P(0, 0);
#pragma unroll
  for (int t = 0; t < 6; ++t) {
    const int cur = t & 1;
    if (t < 5) {
      STAGE_P((t + 1) * 64, cur ^ 1);
      asm volatile("s_waitcnt vmcnt(6)" ::: "memory");  // tile t landed; t+1 in flight
    } else {
      asm volatile("s_waitcnt vmcnt(0)" ::: "memory");
    }
    __builtin_amdgcn_s_barrier();
    const char* bA = (const char*)lsA + cur * 16384;
    const char* bB = (const char*)lsB + cur * 8192;
#pragma unroll
    for (int ks = 0; ks < 2; ++ks) {
      bf16x8 af[4], bfr[2];
#pragma unroll
      for (int i = 0; i < 4; ++i) {
        int row = wm * 64 + i * 16 + l15;
        af[i] = *(const bf16x8*)(bA + row * 128 + (((ks * 4 + g) ^ (row & 7)) << 4));
      }
#pragma unroll
      for (int j = 0; j < 2; ++j) {
        int row = wn * 32 + j * 16 + l15;
        bfr[j] = *(const bf16x8*)(bB + row * 128 + (((ks * 4 + g) ^ (row & 7)) << 4));
      }
#pragma unroll
      for (int i = 0; i < 4; ++i)
#pragma unroll
        for (int j = 0; j < 2; ++j)
          acc[i][j] = mfma_bf16(af[i], bfr[j], acc[i][j]);
    }
    __builtin_amdgcn_s_barrier();
  }
#undef STAGE_P

#pragma unroll
  for (int j = 0; j < 2; ++j) {
    int col = nBase + wn * 32 + j * 16 + l15;
    float bv = bias[col];
#pragma unroll
    for (int i = 0; i < 4; ++i) {
      int m0 = mBase + wm * 64 + i * 16 + g * 4;
#pragma unroll
      for (int r = 0; r < 4; ++r)
        out[(size_t)(m0 + r) * 384 + col] = acc[i][j][r] + bv;
    }
  }
}

// ---------------------------------------------------------------- launch
extern "C" void kernel_launch(void* const* d_in, const int* in_sizes, int n_in,
                              void* d_out, int out_size, void* d_ws, size_t ws_size,
                              hipStream_t stream) {
  const float* x     = (const float*)d_in[0];   // [128,256,384]
  const float* Wqkv  = (const float*)d_in[1];   // [384,1152]
  const float* bqkv  = (const float*)d_in[2];   // [1152]
  const float* Wproj = (const float*)d_in[3];   // [384,384]
  const float* bproj = (const float*)d_in[4];   // [384]
  float* out = (float*)d_out;

  char* ws = (char*)d_ws;
  u16* wqkvb  = (u16*)(ws);                       //    884,736 B
  u16* wprojb = (u16*)(ws + 884736);              //    294,912 B
  u16* Qb     = (u16*)(ws + 1179648);             // [B,H,T,D] 25,165,824 B
  u16* Kb     = (u16*)(ws + 26345472);            // [B,H,T,D]
  u16* Vtb    = (u16*)(ws + 51511296);            // [B,H,D,T]
  u16* Ob     = (u16*)(ws + 76677120);            // [B,T,C]

  k_tcvt<<<1728, 256, 0, stream>>>(Wqkv, wqkvb, 384, 1152);
  k_tcvt<<<576, 256, 0, stream>>>(Wproj, wprojb, 384, 384);
  k_qkv<<<4608, 256, 0, stream>>>(x, wqkvb, bqkv, Qb, Kb, Vtb);
  k_attn<<<dim3(768, 8), 64, 0, stream>>>(Qb, Kb, Vtb, Ob);
  k_proj<<<1536, 256, 0, stream>>>(Ob, wprojb, bproj, out);
}